// Round 1
// 1096.690 us; speedup vs baseline: 1.7822x; 1.7822x over previous
//
#include <hip/hip_runtime.h>
#include <math.h>

#define N_NODES_ 50000
#define N_EDGES_ 1000000
#define HID 128
#define NG 50
#define NF 128
#define NCOL 4
#define CSEG 258048            // 64-aligned per-color capacity (>> 250K + 18 sigma)
#define NKEY (NCOL * N_NODES_) // 200000
#define CHUNK 625              // 50000 = 80 * 625
#define NCHUNK_PER_C 80
#define NCHUNK (NCOL * NCHUNK_PER_C)

typedef short s16x8 __attribute__((ext_vector_type(8)));
typedef float f32x4 __attribute__((ext_vector_type(4)));

__device__ __forceinline__ float sspf(float v) {
    // log(1+e^v) - log2, fast-math; for large v avoid inf
    float r = __logf(1.f + __expf(v)) - 0.69314718055994531f;
    return (v > 15.f) ? (v - 0.69314718055994531f) : r;
}

__device__ __forceinline__ unsigned int f2b(float f) {  // f32 -> bf16 (RNE), in low 16
    unsigned int u = __float_as_uint(f);
    return (u + 0x7fffu + ((u >> 16) & 1u)) >> 16;
}

// ---------------- histogram over (color,dst) keys ----------------
__global__ __launch_bounds__(256) void hist_kernel(const int* __restrict__ colors,
                                                   const int* __restrict__ edge_index,
                                                   int* __restrict__ hist) {
    int e = blockIdx.x * 256 + threadIdx.x;
    if (e < N_EDGES_) {
        int key = colors[e] * N_NODES_ + edge_index[N_EDGES_ + e];
        atomicAdd(&hist[key], 1);
    }
}

// ---------------- per-chunk exclusive scan (in place) ----------------
__global__ __launch_bounds__(256) void scan1_kernel(int* __restrict__ hist,
                                                    int* __restrict__ csum) {
    __shared__ int s[CHUNK];
    int b = blockIdx.x;                  // 0..319
    int c = b / NCHUNK_PER_C, ch = b % NCHUNK_PER_C;
    int gofs = c * N_NODES_ + ch * CHUNK;
    for (int i = threadIdx.x; i < CHUNK; i += 256) s[i] = hist[gofs + i];
    __syncthreads();
    if (threadIdx.x == 0) {
        int run = 0;
        for (int i = 0; i < CHUNK; ++i) { int t = s[i]; s[i] = run; run += t; }
        csum[b] = run;
    }
    __syncthreads();
    for (int i = threadIdx.x; i < CHUNK; i += 256) hist[gofs + i] = s[i];
}

__global__ __launch_bounds__(64) void scan2_kernel(const int* __restrict__ csum,
                                                   int* __restrict__ cbase,
                                                   int* __restrict__ g_cnt) {
    int c = threadIdx.x;
    if (c < NCOL) {
        int run = 0;
        for (int j = 0; j < NCHUNK_PER_C; ++j) {
            cbase[c * NCHUNK_PER_C + j] = run;
            run += csum[c * NCHUNK_PER_C + j];
        }
        g_cnt[c] = run;
    }
}

__global__ __launch_bounds__(256) void scan3_kernel(int* __restrict__ hist,
                                                    const int* __restrict__ cbase) {
    int b = blockIdx.x;
    int c = b / NCHUNK_PER_C, ch = b % NCHUNK_PER_C;
    int gofs = c * N_NODES_ + ch * CHUNK;
    int add = cbase[b];
    for (int i = threadIdx.x; i < CHUNK; i += 256) hist[gofs + i] += add;
}

// ---------------- scatter into (color,dst)-sorted order ----------------
__global__ __launch_bounds__(256) void scatter_kernel(const int* __restrict__ colors,
                                                      const int* __restrict__ edge_index,
                                                      int* __restrict__ base,  // = scanned hist (used as cursor)
                                                      int* __restrict__ eid_s) {
    int e = blockIdx.x * 256 + threadIdx.x;
    if (e < N_EDGES_) {
        int c = colors[e];
        int key = c * N_NODES_ + edge_index[N_EDGES_ + e];
        int r = atomicAdd(&base[key], 1);
        eid_s[c * CSEG + r] = e;
    }
}

// ---------------- convert MLP weights to bf16 (zero-padded K for m1) ----------------
__global__ __launch_bounds__(256) void wconv_kernel(const float* __restrict__ m1w,
                                                    const float* __restrict__ m2w,
                                                    unsigned short* __restrict__ m1b16,
                                                    unsigned short* __restrict__ m2b16) {
    int idx = blockIdx.x * 256 + threadIdx.x;
    if (idx < NCOL * NF * 64) {
        int c = idx / (NF * 64);
        int rem = idx % (NF * 64);
        int n = rem / 64, k = rem % 64;
        float v = (k < NG) ? m1w[(c * NF + n) * NG + k] : 0.f;
        m1b16[idx] = (unsigned short)f2b(v);
    } else if (idx < NCOL * NF * 64 + NCOL * NF * NF) {
        int j = idx - NCOL * NF * 64;
        m2b16[j] = (unsigned short)f2b(m2w[j]);
    }
}

// ---------------- fused edge pass: colored MLP (MFMA bf16) + cutoff + gather +
//                  in-register segmented run reduction + atomic emit ----------------
// Waves are fully independent: eaT/tsT are wave-private (each wave writes/reads its
// own 16 rows), meta is per-lane, run reduction is a shfl segmented suffix-sum.
// No __syncthreads, no accL, no LDS atomics. LDS = 28 KB -> 4 blocks/CU (VGPR-capped).
__global__ __launch_bounds__(256, 4) void passA_kernel(
    const int* __restrict__ edge_index, const float* __restrict__ edge_weight,
    const float* __restrict__ edge_attr,
    const unsigned short* __restrict__ m1b16, const unsigned short* __restrict__ m2b16,
    const float* __restrict__ m1bias, const float* __restrict__ m2bias,
    const float* __restrict__ h, const int* __restrict__ eid_s,
    const int* __restrict__ g_cnt, float* __restrict__ agg) {

    __shared__ __align__(16) unsigned short eaT[64][80];   // [edge][k<=64 padded], wave-private rows
    __shared__ __align__(16) unsigned short tsT[64][144];  // [edge][filter], wave-private rows

    int c = blockIdx.x >> 12;            // 4096 tiles per color
    int tile = blockIdx.x & 4095;
    int cnt = g_cnt[c];
    if (tile * 64 >= cnt) return;
    int pos0 = c * CSEG + tile * 64;

    int tid = threadIdx.x;
    int wv = tid >> 6;
    int l15 = tid & 15;
    int q = (tid >> 4) & 3;
    int e = (wv << 4) | l15;             // this thread's edge row in tile

    // per-lane edge meta (4x redundant across q lanes; all hits same cache lines)
    int eid = eid_s[pos0 + e];
    int sidx = 0, d = -1;
    float cw = 0.f;
    if (eid >= 0) {
        sidx = edge_index[eid];
        d = edge_index[N_EDGES_ + eid];
        float ww = edge_weight[eid];
        cw = 0.5f * (__cosf(ww * 0.31415926535897932f) + 1.f);
    }

    // edge_attr -> bf16 LDS (zero pad k=50..79); rows r = tid>>2 are this wave's own rows
    {
        int r = tid >> 2, j0 = tid & 3;
        int eid2 = eid_s[pos0 + r];
        if (eid2 < 0) eid2 = 0;
        const float* ear = edge_attr + (size_t)eid2 * NG;
#pragma unroll
        for (int j = 0; j < 10; ++j) {
            int i2 = j0 + 4 * j;         // float2 index 0..39
            unsigned int pk = 0;
            if (i2 < 25) {
                float2 v = *(const float2*)(ear + 2 * i2);
                pk = f2b(v.x) | (f2b(v.y) << 16);
            }
            *(unsigned int*)&eaT[r][2 * i2] = pk;
        }
    }
    // no barrier: eaT rows are written and read by the same wave (lgkmcnt ordering)

    // phase 1: t = ssp(m1 @ ea^T + b1)   D rows = filter, cols = edge
    f32x4 acc[8];
#pragma unroll
    for (int m = 0; m < 8; ++m) acc[m] = (f32x4)(0.f);
    {
        const unsigned short* m1p = m1b16 + (size_t)c * NF * 64;
#pragma unroll
        for (int ks = 0; ks < 2; ++ks) {
            s16x8 bfrag = *(const s16x8*)&eaT[e][q * 8 + 32 * ks];
#pragma unroll
            for (int m = 0; m < 8; ++m) {
                s16x8 afrag = *(const s16x8*)(m1p + (m * 16 + l15) * 64 + q * 8 + 32 * ks);
                acc[m] = __builtin_amdgcn_mfma_f32_16x16x32_bf16(afrag, bfrag, acc[m], 0, 0, 0);
            }
        }
    }
    {
        const float* b1p = m1bias + c * NF;
#pragma unroll
        for (int m = 0; m < 8; ++m) {
            int n0 = m * 16 + q * 4;
            f32x4 bv = *(const f32x4*)(b1p + n0);   // L1-hot, 16-way lane-replicated
            float t0 = sspf(acc[m][0] + bv[0]);
            float t1 = sspf(acc[m][1] + bv[1]);
            float t2 = sspf(acc[m][2] + bv[2]);
            float t3 = sspf(acc[m][3] + bv[3]);
            unsigned int p0 = f2b(t0) | (f2b(t1) << 16);
            unsigned int p1 = f2b(t2) | (f2b(t3) << 16);
            uint2 pk; pk.x = p0; pk.y = p1;
            *(uint2*)&tsT[e][n0] = pk;       // same-wave rows: no barrier needed
        }
    }

    // phase 2: u = m2 @ t^T   D rows = filter, cols = edge
    f32x4 acc2[8];
#pragma unroll
    for (int m = 0; m < 8; ++m) acc2[m] = (f32x4)(0.f);
    {
        const unsigned short* m2p = m2b16 + (size_t)c * NF * NF;
#pragma unroll
        for (int ks = 0; ks < 4; ++ks) {
            s16x8 bfrag = *(const s16x8*)&tsT[e][q * 8 + 32 * ks];
#pragma unroll
            for (int m = 0; m < 8; ++m) {
                s16x8 afrag = *(const s16x8*)(m2p + (m * 16 + l15) * NF + q * 8 + 32 * ks);
                acc2[m] = __builtin_amdgcn_mfma_f32_16x16x32_bf16(afrag, bfrag, acc2[m], 0, 0, 0);
            }
        }
    }

    // epilogue: msg = h[src] * (u + b2) * cw, in place in acc2
    {
        const float* hrow = h + (size_t)sidx * HID;
        const float* b2p = m2bias + c * NF;
#pragma unroll
        for (int m = 0; m < 8; ++m) {
            int n0 = m * 16 + q * 4;
            f32x4 hv = *(const f32x4*)(hrow + n0);
            f32x4 bv = *(const f32x4*)(b2p + n0);
            acc2[m][0] = (acc2[m][0] + bv[0]) * cw * hv[0];
            acc2[m][1] = (acc2[m][1] + bv[1]) * cw * hv[1];
            acc2[m][2] = (acc2[m][2] + bv[2]) * cw * hv[2];
            acc2[m][3] = (acc2[m][3] + bv[3]) * cw * hv[3];
        }
    }

    // segmented suffix-sum over the 16-lane edge group (edges dst-sorted, so
    // equal-dst is contiguous): after 4 steps, the first lane of each run holds
    // the full run sum for its 32 filter values.
    int dprev = __shfl_up(d, 1, 16);
#pragma unroll
    for (int dd = 1; dd < 16; dd <<= 1) {
        int dn = __shfl_down(d, dd, 16);
        bool same = (dn == d) && (l15 + dd < 16);
#pragma unroll
        for (int m = 0; m < 8; ++m) {
#pragma unroll
            for (int j = 0; j < 4; ++j) {
                float vn = __shfl_down(acc2[m][j], dd, 16);
                if (same) acc2[m][j] += vn;
            }
        }
    }

    bool head = (d >= 0) && (l15 == 0 || d != dprev);
    if (head) {
        float* ap = agg + (size_t)d * HID + (q << 2);
#pragma unroll
        for (int m = 0; m < 8; ++m) {
            atomicAdd(ap + m * 16 + 0, acc2[m][0]);
            atomicAdd(ap + m * 16 + 1, acc2[m][1]);
            atomicAdd(ap + m * 16 + 2, acc2[m][2]);
            atomicAdd(ap + m * 16 + 3, acc2[m][3]);
        }
    }
}

// ---------------- f32 helpers for lin1 / out (unchanged) ----------------
__device__ __forceinline__ void fma_2x8(float (&acc)[2][8], float2 a, float4 b0, float4 b1) {
    acc[0][0] += a.x * b0.x; acc[0][1] += a.x * b0.y;
    acc[0][2] += a.x * b0.z; acc[0][3] += a.x * b0.w;
    acc[0][4] += a.x * b1.x; acc[0][5] += a.x * b1.y;
    acc[0][6] += a.x * b1.z; acc[0][7] += a.x * b1.w;
    acc[1][0] += a.y * b0.x; acc[1][1] += a.y * b0.y;
    acc[1][2] += a.y * b0.z; acc[1][3] += a.y * b0.w;
    acc[1][4] += a.y * b1.x; acc[1][5] += a.y * b1.y;
    acc[1][6] += a.y * b1.z; acc[1][7] += a.y * b1.w;
}

__device__ __forceinline__ void load_wT32(const float4* __restrict__ w4, int kc,
                                          float (*wT)[132], int tid) {
#pragma unroll
    for (int i = 0; i < 4; ++i) {
        int lin = tid + 256 * i;
        int col = lin >> 3;
        int m = lin & 7;
        float4 v = w4[col * 32 + (kc >> 2) + m];
        wT[4 * m + 0][col] = v.x;
        wT[4 * m + 1][col] = v.y;
        wT[4 * m + 2][col] = v.z;
        wT[4 * m + 3][col] = v.w;
    }
}

__global__ __launch_bounds__(256) void lin1_kernel(const float* __restrict__ x,
                                                   const float* __restrict__ w,
                                                   float* __restrict__ h) {
    __shared__ float xT[HID][36];
    __shared__ float wT[32][132];
    int tid = threadIdx.x;
    int tx = tid & 15, ty = tid >> 4;
    int r0 = blockIdx.x * 32;
    const float4* x4 = (const float4*)x;
#pragma unroll
    for (int i = 0; i < 4; ++i) {
        int lin = tid + 256 * i;
        int r = lin >> 5, m = lin & 31;
        int rr = r0 + r; if (rr > N_NODES_ - 1) rr = N_NODES_ - 1;
        float4 v = x4[rr * 32 + m];
        xT[4 * m + 0][r] = v.x; xT[4 * m + 1][r] = v.y;
        xT[4 * m + 2][r] = v.z; xT[4 * m + 3][r] = v.w;
    }
    float acc[2][8] = {};
    for (int kc = 0; kc < HID; kc += 32) {
        __syncthreads();
        load_wT32((const float4*)w, kc, wT, tid);
        __syncthreads();
#pragma unroll 8
        for (int k2 = 0; k2 < 32; ++k2) {
            float2 a = *(const float2*)&xT[kc + k2][2 * ty];
            float4 b0 = *(const float4*)&wT[k2][8 * tx];
            float4 b1 = *(const float4*)&wT[k2][8 * tx + 4];
            fma_2x8(acc, a, b0, b1);
        }
    }
    float4* h4 = (float4*)h;
#pragma unroll
    for (int i = 0; i < 2; ++i) {
        int row = r0 + 2 * ty + i;
        if (row < N_NODES_) {
            h4[row * 32 + 2 * tx]     = make_float4(acc[i][0], acc[i][1], acc[i][2], acc[i][3]);
            h4[row * 32 + 2 * tx + 1] = make_float4(acc[i][4], acc[i][5], acc[i][6], acc[i][7]);
        }
    }
}

__global__ __launch_bounds__(256) void out_kernel(
    const float* __restrict__ agg,
    const float* __restrict__ w2, const float* __restrict__ b2,
    const float* __restrict__ w3, const float* __restrict__ b3,
    float* __restrict__ out) {
    __shared__ float sT[HID][36];
    __shared__ float wT[32][132];
    int tid = threadIdx.x;
    int tx = tid & 15, ty = tid >> 4;
    int r0 = blockIdx.x * 32;
    const float4* a4 = (const float4*)agg;
#pragma unroll
    for (int i = 0; i < 4; ++i) {
        int lin = tid + 256 * i;
        int r = lin >> 5, m = lin & 31;
        int rr = r0 + r; if (rr > N_NODES_ - 1) rr = N_NODES_ - 1;
        float4 v = a4[rr * 32 + m];
        sT[4 * m + 0][r] = v.x; sT[4 * m + 1][r] = v.y;
        sT[4 * m + 2][r] = v.z; sT[4 * m + 3][r] = v.w;
    }
    float acc[2][8] = {};
    for (int kc = 0; kc < HID; kc += 32) {
        __syncthreads();
        load_wT32((const float4*)w2, kc, wT, tid);
        __syncthreads();
#pragma unroll 8
        for (int k2 = 0; k2 < 32; ++k2) {
            float2 a = *(const float2*)&sT[kc + k2][2 * ty];
            float4 c0 = *(const float4*)&wT[k2][8 * tx];
            float4 c1 = *(const float4*)&wT[k2][8 * tx + 4];
            fma_2x8(acc, a, c0, c1);
        }
    }
    __syncthreads();
#pragma unroll
    for (int j = 0; j < 8; ++j) {
        int col = 8 * tx + j;
        float bbv = b2[col];
        sT[col][2 * ty]     = sspf(acc[0][j] + bbv);
        sT[col][2 * ty + 1] = sspf(acc[1][j] + bbv);
    }
    float acc2[2][8] = {};
    for (int kc = 0; kc < HID; kc += 32) {
        __syncthreads();
        load_wT32((const float4*)w3, kc, wT, tid);
        __syncthreads();
#pragma unroll 8
        for (int k2 = 0; k2 < 32; ++k2) {
            float2 a = *(const float2*)&sT[kc + k2][2 * ty];
            float4 c0 = *(const float4*)&wT[k2][8 * tx];
            float4 c1 = *(const float4*)&wT[k2][8 * tx + 4];
            fma_2x8(acc2, a, c0, c1);
        }
    }
    float4* out4 = (float4*)out;
#pragma unroll
    for (int i = 0; i < 2; ++i) {
        int row = r0 + 2 * ty + i;
        if (row < N_NODES_) {
            out4[row * 32 + 2 * tx] = make_float4(
                acc2[i][0] + b3[8 * tx + 0], acc2[i][1] + b3[8 * tx + 1],
                acc2[i][2] + b3[8 * tx + 2], acc2[i][3] + b3[8 * tx + 3]);
            out4[row * 32 + 2 * tx + 1] = make_float4(
                acc2[i][4] + b3[8 * tx + 4], acc2[i][5] + b3[8 * tx + 5],
                acc2[i][6] + b3[8 * tx + 6], acc2[i][7] + b3[8 * tx + 7]);
        }
    }
}

extern "C" void kernel_launch(void* const* d_in, const int* in_sizes, int n_in,
                              void* d_out, int out_size, void* d_ws, size_t ws_size,
                              hipStream_t stream) {
    const float* x           = (const float*)d_in[0];
    const int*   edge_index  = (const int*)d_in[1];
    const float* edge_weight = (const float*)d_in[2];
    const float* edge_attr   = (const float*)d_in[3];
    const int*   colors      = (const int*)d_in[4];
    const float* m1w         = (const float*)d_in[5];
    const float* m1b         = (const float*)d_in[6];
    const float* m2w         = (const float*)d_in[7];
    const float* m2b         = (const float*)d_in[8];
    const float* lin1w       = (const float*)d_in[9];
    const float* lin2w       = (const float*)d_in[10];
    const float* lin2b       = (const float*)d_in[11];
    const float* linw        = (const float*)d_in[12];
    const float* linb        = (const float*)d_in[13];
    float* out = (float*)d_out;

    // workspace layout (bytes)
    char* ws = (char*)d_ws;
    float* h      = (float*)(ws);                         // 25,600,000
    float* agg    = (float*)(ws + 25600000);              // 25,600,000
    int*   eid_s  = (int*)(ws + 51200000);                // 4*CSEG*4 = 4,128,768
    int*   base   = (int*)(ws + 55328768);                // NKEY*4 = 800,000
    int*   csum   = (int*)(ws + 56128768);                // 1,280
    int*   cbase  = (int*)(ws + 56130048);                // 1,280
    int*   g_cnt  = (int*)(ws + 56131328);                // 64
    unsigned short* m1b16 = (unsigned short*)(ws + 56131392);  // 65,536
    unsigned short* m2b16 = (unsigned short*)(ws + 56196928);  // 131,072
    // end ~56.33 MB

    hipMemsetAsync(agg, 0, (size_t)N_NODES_ * HID * sizeof(float), stream);
    hipMemsetAsync(base, 0, NKEY * sizeof(int), stream);
    hipMemsetAsync(eid_s, 0xFF, (size_t)NCOL * CSEG * sizeof(int), stream);  // -1 pads

    hist_kernel<<<(N_EDGES_ + 255) / 256, 256, 0, stream>>>(colors, edge_index, base);
    scan1_kernel<<<NCHUNK, 256, 0, stream>>>(base, csum);
    scan2_kernel<<<1, 64, 0, stream>>>(csum, cbase, g_cnt);
    scan3_kernel<<<NCHUNK, 256, 0, stream>>>(base, cbase);
    scatter_kernel<<<(N_EDGES_ + 255) / 256, 256, 0, stream>>>(colors, edge_index, base, eid_s);
    wconv_kernel<<<(NCOL * NF * 64 + NCOL * NF * NF + 255) / 256, 256, 0, stream>>>(m1w, m2w, m1b16, m2b16);
    lin1_kernel<<<(N_NODES_ + 31) / 32, 256, 0, stream>>>(x, lin1w, h);
    passA_kernel<<<NCOL * 4096, 256, 0, stream>>>(edge_index, edge_weight, edge_attr,
                                                  m1b16, m2b16, m1b, m2b, h, eid_s, g_cnt, agg);
    out_kernel<<<(N_NODES_ + 31) / 32, 256, 0, stream>>>(agg, lin2w, lin2b, linw, linb, out);
}